// Round 1
// baseline (3065.752 us; speedup 1.0000x reference)
//
#include <hip/hip_runtime.h>
#include <math.h>

// Problem constants
#define LL 4096
#define DD 1024
#define NN 16
#define KK 4
#define BB 2
#define MM (BB * LL)   // 8192

// ---------------------------------------------------------------------------
// GEMM: C[M,N] = A[M,1024] @ W[1024,N] + bias[N]
// 64x64 tile, BK=16, 256 threads, 4x4 micro-tile per thread. N may be < 64
// (B/C projection, N=32) -> guarded loads/stores on the N dimension.
// ---------------------------------------------------------------------------
__global__ __launch_bounds__(256) void gemm_bias_k(
    const float* __restrict__ A, const float* __restrict__ W,
    const float* __restrict__ bias, float* __restrict__ C, int N) {
  constexpr int K = 1024;
  __shared__ float As[16][65];  // [k][row], pad 65 to break store conflicts
  __shared__ float Ws[16][64];  // [k][col]

  const int tid = threadIdx.x;
  const int tx = tid & 15, ty = tid >> 4;
  const int row0 = blockIdx.y * 64;
  const int n0 = blockIdx.x * 64;

  // A-tile load mapping: thread -> (row, 4 consecutive k)
  const int arow = tid >> 2;        // 0..63
  const int akk = (tid & 3) * 4;    // 0,4,8,12
  // W-tile load mapping: thread -> (k, col), 4 k's per thread
  const int wn = tid & 63;          // 0..63
  const int wk0 = tid >> 6;         // 0..3

  float acc[4][4] = {{0.f}};

  for (int k0 = 0; k0 < K; k0 += 16) {
    float4 av = *(const float4*)&A[(size_t)(row0 + arow) * K + k0 + akk];
    float wv[4];
#pragma unroll
    for (int i = 0; i < 4; ++i) {
      int col = n0 + wn;
      wv[i] = (col < N) ? W[(size_t)(k0 + wk0 + i * 4) * N + col] : 0.f;
    }
    __syncthreads();  // previous tile fully consumed
    As[akk + 0][arow] = av.x;
    As[akk + 1][arow] = av.y;
    As[akk + 2][arow] = av.z;
    As[akk + 3][arow] = av.w;
#pragma unroll
    for (int i = 0; i < 4; ++i) Ws[wk0 + i * 4][wn] = wv[i];
    __syncthreads();
#pragma unroll
    for (int kk = 0; kk < 16; ++kk) {
      float a[4];
#pragma unroll
      for (int i = 0; i < 4; ++i) a[i] = As[kk][ty * 4 + i];
      float4 w4 = *(const float4*)&Ws[kk][tx * 4];
#pragma unroll
      for (int i = 0; i < 4; ++i) {
        acc[i][0] += a[i] * w4.x;
        acc[i][1] += a[i] * w4.y;
        acc[i][2] += a[i] * w4.z;
        acc[i][3] += a[i] * w4.w;
      }
    }
  }
#pragma unroll
  for (int i = 0; i < 4; ++i) {
    int r = row0 + ty * 4 + i;
#pragma unroll
    for (int j = 0; j < 4; ++j) {
      int c = n0 + tx * 4 + j;
      if (c < N) C[(size_t)r * N + c] = acc[i][j] + bias[c];
    }
  }
}

// ---------------------------------------------------------------------------
// Depthwise causal conv (left pad K-1) + SiLU.
// XG is [M, 2048]; x_ssm = cols [0,1024). Output XC [M, 1024].
// ---------------------------------------------------------------------------
__global__ __launch_bounds__(256) void conv_silu_k(
    const float* __restrict__ XG, const float* __restrict__ conv_w,
    const float* __restrict__ conv_b, float* __restrict__ XC) {
  int idx = blockIdx.x * 256 + threadIdx.x;  // over M*D
  int d = idx & (DD - 1);
  int m = idx >> 10;
  int b = m >> 12;       // m / 4096
  int l = m & (LL - 1);  // m % 4096
  float v = conv_b[d];
#pragma unroll
  for (int k = 0; k < KK; ++k) {
    int li = l + k - (KK - 1);
    if (li >= 0) v += XG[((size_t)(b * LL + li)) * 2048 + d] * conv_w[d * KK + k];
  }
  float s = v / (1.f + __expf(-v));  // silu
  XC[(size_t)m * DD + d] = s;
}

// ---------------------------------------------------------------------------
// Zero the 32-float final_state region (d_out is poisoned before every call).
// ---------------------------------------------------------------------------
__global__ void zero_fs_k(float* fs) {
  if (threadIdx.x < 32) fs[threadIdx.x] = 0.f;
}

// ---------------------------------------------------------------------------
// Selective scan. Grid (B, D/64), 64 threads; each thread owns one d, keeps
// h[16] in registers. B_t/C_t (32 floats) double-buffered in LDS; xc/gate
// prefetched one step ahead. Fuses y *= silu(gate) and the final-state mean.
// ---------------------------------------------------------------------------
__global__ __launch_bounds__(64) void scan_k(
    const float* __restrict__ XC, const float* __restrict__ XG,
    const float* __restrict__ BC, const float* __restrict__ A_log,
    const float* __restrict__ D_param, float* __restrict__ Y1,
    float* __restrict__ fs) {
  const int b = blockIdx.x;
  const int d = blockIdx.y * 64 + threadIdx.x;
  const int tid = threadIdx.x;

  float Ad[NN], h[NN];
#pragma unroll
  for (int n = 0; n < NN; ++n) {
    Ad[n] = expf(-expf(A_log[d * NN + n]));
    h[n] = 0.f;
  }
  const float Dp = D_param[d];

  __shared__ float bc[2][32];
  const size_t rowb = (size_t)b * LL;
  if (tid < 32) bc[0][tid] = BC[rowb * 32 + tid];
  float xc = XC[rowb * DD + d];
  float gate = XG[rowb * 2048 + DD + d];
  __syncthreads();

  int cur = 0;
  for (int t = 0; t < LL; ++t) {
    float xc_n = 0.f, gate_n = 0.f;
    if (t + 1 < LL) {
      xc_n = XC[(rowb + t + 1) * DD + d];
      gate_n = XG[(rowb + t + 1) * 2048 + DD + d];
      if (tid < 32) bc[1 - cur][tid] = BC[(rowb + t + 1) * 32 + tid];
    }
    float y = Dp * xc;
#pragma unroll
    for (int n = 0; n < NN; ++n) {
      h[n] = Ad[n] * h[n] + xc * bc[cur][n];
      y += bc[cur][16 + n] * h[n];
    }
    float sg = gate / (1.f + __expf(-gate));
    Y1[(rowb + t) * DD + d] = y * sg;
    xc = xc_n;
    gate = gate_n;
    __syncthreads();  // next-buffer writes done; current buffer free
    cur ^= 1;
  }

  // final_state: mean over D of h -> [b, n]
#pragma unroll
  for (int n = 0; n < NN; ++n) {
    float v = h[n];
#pragma unroll
    for (int off = 32; off > 0; off >>= 1) v += __shfl_down(v, off);
    if (tid == 0) atomicAdd(&fs[b * NN + n], v * (1.f / (float)DD));
  }
}

// ---------------------------------------------------------------------------
extern "C" void kernel_launch(void* const* d_in, const int* in_sizes, int n_in,
                              void* d_out, int out_size, void* d_ws,
                              size_t ws_size, hipStream_t stream) {
  const float* x = (const float*)d_in[0];
  const float* W_in = (const float*)d_in[1];
  const float* b_in = (const float*)d_in[2];
  const float* conv_w = (const float*)d_in[3];
  const float* conv_b = (const float*)d_in[4];
  const float* W_x = (const float*)d_in[5];
  const float* b_x = (const float*)d_in[6];
  const float* A_log = (const float*)d_in[7];
  const float* D_param = (const float*)d_in[8];
  const float* W_out = (const float*)d_in[9];
  const float* b_out = (const float*)d_in[10];
  float* out = (float*)d_out;

  // workspace layout (floats): XG[8192*2048] XC[8192*1024] BC[8192*32] Y1[8192*1024]
  float* XG = (float*)d_ws;
  float* XC = XG + (size_t)MM * 2048;
  float* BC = XC + (size_t)MM * DD;
  float* Y1 = BC + (size_t)MM * 32;

  dim3 blk(256);
  // 1. in-proj: XG = x @ W_in + b_in   [8192, 2048]
  gemm_bias_k<<<dim3(2048 / 64, MM / 64), blk, 0, stream>>>(x, W_in, b_in, XG, 2048);
  // 2. depthwise causal conv + silu -> XC [8192, 1024]
  conv_silu_k<<<dim3((MM * DD) / 256), blk, 0, stream>>>(XG, conv_w, conv_b, XC);
  // 3. B/C proj: BC = XC @ W_x + b_x   [8192, 32]
  gemm_bias_k<<<dim3(1, MM / 64), blk, 0, stream>>>(XC, W_x, b_x, BC, 32);
  // 4. zero final_state accumulator region of d_out
  zero_fs_k<<<dim3(1), dim3(64), 0, stream>>>(out + (size_t)MM * DD);
  // 5. selective scan (+ gate fusion, final-state mean)
  scan_k<<<dim3(BB, DD / 64), dim3(64), 0, stream>>>(XC, XG, BC, A_log, D_param,
                                                     Y1, out + (size_t)MM * DD);
  // 6. out-proj: out = Y1 @ W_out + b_out  [8192, 1024]
  gemm_bias_k<<<dim3(1024 / 64, MM / 64), blk, 0, stream>>>(Y1, W_out, b_out, out, 1024);
}

// Round 2
// 1023.291 us; speedup vs baseline: 2.9960x; 2.9960x over previous
//
#include <hip/hip_runtime.h>
#include <math.h>

// Problem constants
#define LL 4096
#define DD 1024
#define NN 16
#define KK 4
#define BB 2
#define MM (BB * LL)   // 8192
#define NC 64          // scan chunks
#define LC 64          // chunk length (NC*LC == LL)

// ---------------------------------------------------------------------------
// GEMM: C[M,N] = A[M,1024] @ W[1024,N] + bias[N]
// 64x64 tile, BK=16, 256 threads, 4x4 micro-tile per thread.
// ---------------------------------------------------------------------------
__global__ __launch_bounds__(256) void gemm_bias_k(
    const float* __restrict__ A, const float* __restrict__ W,
    const float* __restrict__ bias, float* __restrict__ C, int N) {
  constexpr int K = 1024;
  __shared__ float As[16][65];
  __shared__ float Ws[16][64];

  const int tid = threadIdx.x;
  const int tx = tid & 15, ty = tid >> 4;
  const int row0 = blockIdx.y * 64;
  const int n0 = blockIdx.x * 64;

  const int arow = tid >> 2;
  const int akk = (tid & 3) * 4;
  const int wn = tid & 63;
  const int wk0 = tid >> 6;

  float acc[4][4] = {{0.f}};

  for (int k0 = 0; k0 < K; k0 += 16) {
    float4 av = *(const float4*)&A[(size_t)(row0 + arow) * K + k0 + akk];
    float wv[4];
#pragma unroll
    for (int i = 0; i < 4; ++i) {
      int col = n0 + wn;
      wv[i] = (col < N) ? W[(size_t)(k0 + wk0 + i * 4) * N + col] : 0.f;
    }
    __syncthreads();
    As[akk + 0][arow] = av.x;
    As[akk + 1][arow] = av.y;
    As[akk + 2][arow] = av.z;
    As[akk + 3][arow] = av.w;
#pragma unroll
    for (int i = 0; i < 4; ++i) Ws[wk0 + i * 4][wn] = wv[i];
    __syncthreads();
#pragma unroll
    for (int kk = 0; kk < 16; ++kk) {
      float a[4];
#pragma unroll
      for (int i = 0; i < 4; ++i) a[i] = As[kk][ty * 4 + i];
      float4 w4 = *(const float4*)&Ws[kk][tx * 4];
#pragma unroll
      for (int i = 0; i < 4; ++i) {
        acc[i][0] += a[i] * w4.x;
        acc[i][1] += a[i] * w4.y;
        acc[i][2] += a[i] * w4.z;
        acc[i][3] += a[i] * w4.w;
      }
    }
  }
#pragma unroll
  for (int i = 0; i < 4; ++i) {
    int r = row0 + ty * 4 + i;
#pragma unroll
    for (int j = 0; j < 4; ++j) {
      int c = n0 + tx * 4 + j;
      if (c < N) C[(size_t)r * N + c] = acc[i][j] + bias[c];
    }
  }
}

// ---------------------------------------------------------------------------
// Depthwise causal conv (left pad K-1) + SiLU. XG [M,2048] -> XC [M,1024].
// ---------------------------------------------------------------------------
__global__ __launch_bounds__(256) void conv_silu_k(
    const float* __restrict__ XG, const float* __restrict__ conv_w,
    const float* __restrict__ conv_b, float* __restrict__ XC) {
  int idx = blockIdx.x * 256 + threadIdx.x;
  int d = idx & (DD - 1);
  int m = idx >> 10;
  int b = m >> 12;
  int l = m & (LL - 1);
  float v = conv_b[d];
#pragma unroll
  for (int k = 0; k < KK; ++k) {
    int li = l + k - (KK - 1);
    if (li >= 0) v += XG[((size_t)(b * LL + li)) * 2048 + d] * conv_w[d * KK + k];
  }
  float s = v / (1.f + __expf(-v));
  XC[(size_t)m * DD + d] = s;
}

__global__ void zero_fs_k(float* fs) {
  if (threadIdx.x < 32) fs[threadIdx.x] = 0.f;
}

// ---------------------------------------------------------------------------
// Scan phase 1: per-chunk local scan from h=0; store chunk end-state S.
// Grid (B, NC, D/64), 64 threads, one d per thread, h[16] in regs.
// ---------------------------------------------------------------------------
__global__ __launch_bounds__(64) void scan_local_k(
    const float* __restrict__ XC, const float* __restrict__ BC,
    const float* __restrict__ A_log, float* __restrict__ S) {
  const int b = blockIdx.x, c = blockIdx.y;
  const int tid = threadIdx.x;
  const int d = blockIdx.z * 64 + tid;
  const int t0 = c * LC;
  const size_t rowb = (size_t)b * LL;

  __shared__ float bc[LC * 32];  // whole chunk's B/C rows, 8 KB
  {
    const float4* src = (const float4*)(BC + (rowb + t0) * 32);
    float4* dst = (float4*)bc;
#pragma unroll
    for (int i = 0; i < 8; ++i) dst[tid + i * 64] = src[tid + i * 64];
  }

  float a[NN], h[NN];
#pragma unroll
  for (int n = 0; n < NN; ++n) {
    a[n] = expf(-expf(A_log[d * NN + n]));
    h[n] = 0.f;
  }
  __syncthreads();

  const float* xp = XC + (rowb + t0) * DD + d;
  float xc = *xp;
  for (int t = 0; t < LC; ++t) {
    float xc_n = (t + 1 < LC) ? xp[(t + 1) * DD] : 0.f;
#pragma unroll
    for (int n = 0; n < NN; ++n) h[n] = a[n] * h[n] + xc * bc[t * 32 + n];
    xc = xc_n;
  }
  float* sp = S + (((size_t)(b * NC + c)) * DD + d) * NN;
#pragma unroll
  for (int n = 0; n < NN; ++n) sp[n] = h[n];
}

// ---------------------------------------------------------------------------
// Scan phase 2: sequential carry over chunks (in-place: S -> H0), fused
// final-state mean. One thread per (b,d,n); 64-step loop.
// ---------------------------------------------------------------------------
__global__ __launch_bounds__(256) void scan_carry_k(
    float* __restrict__ S, const float* __restrict__ A_log,
    float* __restrict__ fs) {
  const int idx = blockIdx.x * 256 + threadIdx.x;  // (b*DD+d)*NN+n
  const int n = idx & (NN - 1);
  const int d = (idx / NN) & (DD - 1);
  const int b = idx / (NN * DD);

  const float aLC = expf(-(float)LC * expf(A_log[d * NN + n]));
  float h = 0.f;
  for (int c = 0; c < NC; ++c) {
    size_t off = (((size_t)(b * NC + c)) * DD + d) * NN + n;
    float s = S[off];
    S[off] = h;          // becomes H0 for chunk c
    h = aLC * h + s;
  }
  // h is now the final state for (b,d,n); mean over d.
  __shared__ float red[256];
  red[threadIdx.x] = h * (1.f / (float)DD);
  __syncthreads();
  if (threadIdx.x < NN) {
    float sum = 0.f;
#pragma unroll
    for (int i = 0; i < 16; ++i) sum += red[i * NN + threadIdx.x];
    atomicAdd(&fs[b * NN + threadIdx.x], sum);
  }
}

// ---------------------------------------------------------------------------
// Scan phase 3: replay each chunk from its H0, produce y * silu(gate).
// ---------------------------------------------------------------------------
__global__ __launch_bounds__(64) void scan_final_k(
    const float* __restrict__ XC, const float* __restrict__ XG,
    const float* __restrict__ BC, const float* __restrict__ A_log,
    const float* __restrict__ D_param, const float* __restrict__ H0,
    float* __restrict__ Y1) {
  const int b = blockIdx.x, c = blockIdx.y;
  const int tid = threadIdx.x;
  const int d = blockIdx.z * 64 + tid;
  const int t0 = c * LC;
  const size_t rowb = (size_t)b * LL;

  __shared__ float bc[LC * 32];
  {
    const float4* src = (const float4*)(BC + (rowb + t0) * 32);
    float4* dst = (float4*)bc;
#pragma unroll
    for (int i = 0; i < 8; ++i) dst[tid + i * 64] = src[tid + i * 64];
  }

  float a[NN], h[NN];
  const float* hp = H0 + (((size_t)(b * NC + c)) * DD + d) * NN;
#pragma unroll
  for (int n = 0; n < NN; ++n) {
    a[n] = expf(-expf(A_log[d * NN + n]));
    h[n] = hp[n];
  }
  const float Dp = D_param[d];
  __syncthreads();

  const float* xp = XC + (rowb + t0) * DD + d;
  const float* gp = XG + (rowb + t0) * 2048 + DD + d;
  float* yp = Y1 + (rowb + t0) * DD + d;
  float xc = *xp, gate = *gp;
  for (int t = 0; t < LC; ++t) {
    float xc_n = 0.f, g_n = 0.f;
    if (t + 1 < LC) {
      xc_n = xp[(t + 1) * DD];
      g_n = gp[(t + 1) * 2048];
    }
    float y = Dp * xc;
#pragma unroll
    for (int n = 0; n < NN; ++n) {
      h[n] = a[n] * h[n] + xc * bc[t * 32 + n];
      y += bc[t * 32 + 16 + n] * h[n];
    }
    float sg = gate / (1.f + __expf(-gate));
    yp[t * DD] = y * sg;
    xc = xc_n;
    gate = g_n;
  }
}

// ---------------------------------------------------------------------------
extern "C" void kernel_launch(void* const* d_in, const int* in_sizes, int n_in,
                              void* d_out, int out_size, void* d_ws,
                              size_t ws_size, hipStream_t stream) {
  const float* x = (const float*)d_in[0];
  const float* W_in = (const float*)d_in[1];
  const float* b_in = (const float*)d_in[2];
  const float* conv_w = (const float*)d_in[3];
  const float* conv_b = (const float*)d_in[4];
  const float* W_x = (const float*)d_in[5];
  const float* b_x = (const float*)d_in[6];
  const float* A_log = (const float*)d_in[7];
  const float* D_param = (const float*)d_in[8];
  const float* W_out = (const float*)d_in[9];
  const float* b_out = (const float*)d_in[10];
  float* out = (float*)d_out;

  // ws layout (floats): XG[8192*2048] XC[8192*1024] BC[8192*32] Y1[8192*1024]
  //                     S/H0[B*NC*D*N]
  float* XG = (float*)d_ws;
  float* XC = XG + (size_t)MM * 2048;
  float* BC = XC + (size_t)MM * DD;
  float* Y1 = BC + (size_t)MM * 32;
  float* S = Y1 + (size_t)MM * DD;  // 2*64*1024*16 = 2M floats, becomes H0

  dim3 blk(256);
  // 1. in-proj: XG = x @ W_in + b_in   [8192, 2048]
  gemm_bias_k<<<dim3(2048 / 64, MM / 64), blk, 0, stream>>>(x, W_in, b_in, XG, 2048);
  // 2. depthwise causal conv + silu -> XC
  conv_silu_k<<<dim3((MM * DD) / 256), blk, 0, stream>>>(XG, conv_w, conv_b, XC);
  // 3. B/C proj: BC = XC @ W_x + b_x   [8192, 32]
  gemm_bias_k<<<dim3(1, MM / 64), blk, 0, stream>>>(XC, W_x, b_x, BC, 32);
  // 4. scan phase 1: per-chunk local scans
  scan_local_k<<<dim3(BB, NC, DD / 64), dim3(64), 0, stream>>>(XC, BC, A_log, S);
  // 5. zero final_state accumulator
  zero_fs_k<<<dim3(1), dim3(64), 0, stream>>>(out + (size_t)MM * DD);
  // 6. scan phase 2: carry combine (S -> H0 in place) + final-state mean
  scan_carry_k<<<dim3((BB * DD * NN) / 256), blk, 0, stream>>>(
      S, A_log, out + (size_t)MM * DD);
  // 7. scan phase 3: replay with proper initial states, gate fusion
  scan_final_k<<<dim3(BB, NC, DD / 64), dim3(64), 0, stream>>>(
      XC, XG, BC, A_log, D_param, S, Y1);
  // 8. out-proj: out = Y1 @ W_out + b_out  [8192, 1024]
  gemm_bias_k<<<dim3(1024 / 64, MM / 64), blk, 0, stream>>>(Y1, W_out, b_out, out, 1024);
}

// Round 3
// 369.507 us; speedup vs baseline: 8.2969x; 2.7693x over previous
//
#include <hip/hip_runtime.h>
#include <hip/hip_bf16.h>
#include <math.h>

// Problem constants
#define LL 4096
#define DD 1024
#define NN 16
#define KK 4
#define BB 2
#define MM (BB * LL)   // 8192
#define NC 64          // scan chunks
#define LC 64          // chunk length (NC*LC == LL)

typedef unsigned short ushort_t;
typedef short s16x8 __attribute__((ext_vector_type(8)));
typedef float f32x4 __attribute__((ext_vector_type(4)));
typedef unsigned int u32;

__device__ __forceinline__ ushort_t f2bf(float f) {
  __hip_bfloat16 h = __float2bfloat16(f);
  return *reinterpret_cast<ushort_t*>(&h);
}

// ---------------------------------------------------------------------------
// bf16 MFMA GEMM, B-transposed: C[M,N] = A[M,K] @ BT[N,K]^T + bias, K=1024.
// 128x128 tile, BK=32, 256 threads (4 waves, 2x2), 16x16x32 MFMA,
// global_load_lds width-16 staging (m97 structure).
// ---------------------------------------------------------------------------
__global__ __launch_bounds__(256) void gemm_bt_mfma(
    const ushort_t* __restrict__ A,   // [M,K] bf16
    const ushort_t* __restrict__ BT,  // [N,K] bf16
    const float* __restrict__ bias,
    float* __restrict__ C, int N) {
  constexpr int K = 1024;
  __shared__ ushort_t As[128 * 32];
  __shared__ ushort_t Bs[128 * 32];

  const int tid = threadIdx.x;
  const int lane = tid & 63;
  const int w = tid >> 6;            // wave 0..3
  const int wm = w & 1, wn = w >> 1; // 2x2 wave grid over the 128x128 tile
  const int row0 = blockIdx.y * 128;
  const int col0 = blockIdx.x * 128;

  const int lrow = lane >> 2;        // 0..15: row within 16-row group
  const int lk = (lane & 3) * 8;     // 0,8,16,24: k-chunk (8 bf16 = 16B)

  f32x4 acc[4][4];
#pragma unroll
  for (int i = 0; i < 4; ++i)
#pragma unroll
    for (int j = 0; j < 4; ++j) acc[i][j] = (f32x4){0.f, 0.f, 0.f, 0.f};

  const int frow = lane & 15;
  const int quad = lane >> 4;

  for (int k0 = 0; k0 < K; k0 += 32) {
#pragma unroll
    for (int it = 0; it < 2; ++it) {
      int r = it * 64 + w * 16;  // wave-uniform 16-row group
      __builtin_amdgcn_global_load_lds(
          (const __attribute__((address_space(1))) u32*)(A + (size_t)(row0 + r + lrow) * K + k0 + lk),
          (__attribute__((address_space(3))) u32*)(As + r * 32), 16, 0, 0);
      __builtin_amdgcn_global_load_lds(
          (const __attribute__((address_space(1))) u32*)(BT + (size_t)(col0 + r + lrow) * K + k0 + lk),
          (__attribute__((address_space(3))) u32*)(Bs + r * 32), 16, 0, 0);
    }
    __syncthreads();

    s16x8 af[4], bf[4];
#pragma unroll
    for (int mi = 0; mi < 4; ++mi)
      af[mi] = *(const s16x8*)&As[(wm * 64 + mi * 16 + frow) * 32 + quad * 8];
#pragma unroll
    for (int ni = 0; ni < 4; ++ni)
      bf[ni] = *(const s16x8*)&Bs[(wn * 64 + ni * 16 + frow) * 32 + quad * 8];
#pragma unroll
    for (int mi = 0; mi < 4; ++mi)
#pragma unroll
      for (int ni = 0; ni < 4; ++ni)
        acc[mi][ni] = __builtin_amdgcn_mfma_f32_16x16x32_bf16(
            af[mi], bf[ni], acc[mi][ni], 0, 0, 0);
    __syncthreads();
  }

  // Epilogue: C/D layout col=lane&15, row=quad*4+reg
#pragma unroll
  for (int mi = 0; mi < 4; ++mi) {
#pragma unroll
    for (int ni = 0; ni < 4; ++ni) {
      int col = col0 + wn * 64 + ni * 16 + frow;
      float b = bias[col];
#pragma unroll
      for (int r = 0; r < 4; ++r) {
        int row = row0 + wm * 64 + mi * 16 + quad * 4 + r;
        C[(size_t)row * N + col] = acc[mi][ni][r] + b;
      }
    }
  }
}

// ---------------------------------------------------------------------------
// fp32 -> bf16 cast (vectorized, 4 floats/thread)
// ---------------------------------------------------------------------------
__global__ __launch_bounds__(256) void cast_bf16_k(
    const float* __restrict__ src, ushort_t* __restrict__ dst) {
  int i = blockIdx.x * 256 + threadIdx.x;
  float4 v = ((const float4*)src)[i];
  ushort4 o;
  o.x = f2bf(v.x); o.y = f2bf(v.y); o.z = f2bf(v.z); o.w = f2bf(v.w);
  ((ushort4*)dst)[i] = o;
}

// ---------------------------------------------------------------------------
// W [K,N] fp32 -> WT [N,K] bf16 (tiled transpose via LDS)
// ---------------------------------------------------------------------------
__global__ __launch_bounds__(256) void transpose_cast_k(
    const float* __restrict__ W, ushort_t* __restrict__ WT, int K, int N) {
  __shared__ float t[32][33];
  int nb = blockIdx.x * 32, kb = blockIdx.y * 32;
  int tx = threadIdx.x, ty = threadIdx.y;  // (32,8)
#pragma unroll
  for (int i = 0; i < 32; i += 8)
    t[ty + i][tx] = W[(size_t)(kb + ty + i) * N + nb + tx];
  __syncthreads();
#pragma unroll
  for (int i = 0; i < 32; i += 8)
    WT[(size_t)(nb + ty + i) * K + kb + tx] = f2bf(t[tx][ty + i]);
}

// ---------------------------------------------------------------------------
// fp32 GEMM (kept for the small BC projection, N=32): 64x64 tile.
// ---------------------------------------------------------------------------
__global__ __launch_bounds__(256) void gemm_bias_k(
    const float* __restrict__ A, const float* __restrict__ W,
    const float* __restrict__ bias, float* __restrict__ C, int N) {
  constexpr int K = 1024;
  __shared__ float As[16][65];
  __shared__ float Ws[16][64];

  const int tid = threadIdx.x;
  const int tx = tid & 15, ty = tid >> 4;
  const int row0 = blockIdx.y * 64;
  const int n0 = blockIdx.x * 64;

  const int arow = tid >> 2;
  const int akk = (tid & 3) * 4;
  const int wn = tid & 63;
  const int wk0 = tid >> 6;

  float acc[4][4] = {{0.f}};

  for (int k0 = 0; k0 < K; k0 += 16) {
    float4 av = *(const float4*)&A[(size_t)(row0 + arow) * K + k0 + akk];
    float wv[4];
#pragma unroll
    for (int i = 0; i < 4; ++i) {
      int col = n0 + wn;
      wv[i] = (col < N) ? W[(size_t)(k0 + wk0 + i * 4) * N + col] : 0.f;
    }
    __syncthreads();
    As[akk + 0][arow] = av.x;
    As[akk + 1][arow] = av.y;
    As[akk + 2][arow] = av.z;
    As[akk + 3][arow] = av.w;
#pragma unroll
    for (int i = 0; i < 4; ++i) Ws[wk0 + i * 4][wn] = wv[i];
    __syncthreads();
#pragma unroll
    for (int kk = 0; kk < 16; ++kk) {
      float a[4];
#pragma unroll
      for (int i = 0; i < 4; ++i) a[i] = As[kk][ty * 4 + i];
      float4 w4 = *(const float4*)&Ws[kk][tx * 4];
#pragma unroll
      for (int i = 0; i < 4; ++i) {
        acc[i][0] += a[i] * w4.x;
        acc[i][1] += a[i] * w4.y;
        acc[i][2] += a[i] * w4.z;
        acc[i][3] += a[i] * w4.w;
      }
    }
  }
#pragma unroll
  for (int i = 0; i < 4; ++i) {
    int r = row0 + ty * 4 + i;
#pragma unroll
    for (int j = 0; j < 4; ++j) {
      int c = n0 + tx * 4 + j;
      if (c < N) C[(size_t)r * N + c] = acc[i][j] + bias[c];
    }
  }
}

// ---------------------------------------------------------------------------
// Depthwise causal conv (left pad K-1) + SiLU. XG [M,2048] -> XC [M,1024] f32.
// ---------------------------------------------------------------------------
__global__ __launch_bounds__(256) void conv_silu_k(
    const float* __restrict__ XG, const float* __restrict__ conv_w,
    const float* __restrict__ conv_b, float* __restrict__ XC) {
  int idx = blockIdx.x * 256 + threadIdx.x;
  int d = idx & (DD - 1);
  int m = idx >> 10;
  int b = m >> 12;
  int l = m & (LL - 1);
  float v = conv_b[d];
#pragma unroll
  for (int k = 0; k < KK; ++k) {
    int li = l + k - (KK - 1);
    if (li >= 0) v += XG[((size_t)(b * LL + li)) * 2048 + d] * conv_w[d * KK + k];
  }
  float s = v / (1.f + __expf(-v));
  XC[(size_t)m * DD + d] = s;
}

__global__ void zero_fs_k(float* fs) {
  if (threadIdx.x < 32) fs[threadIdx.x] = 0.f;
}

// ---------------------------------------------------------------------------
// Scan phase 1: per-chunk local scan from h=0; store chunk end-state S.
// ---------------------------------------------------------------------------
__global__ __launch_bounds__(64) void scan_local_k(
    const float* __restrict__ XC, const float* __restrict__ BC,
    const float* __restrict__ A_log, float* __restrict__ S) {
  const int b = blockIdx.x, c = blockIdx.y;
  const int tid = threadIdx.x;
  const int d = blockIdx.z * 64 + tid;
  const int t0 = c * LC;
  const size_t rowb = (size_t)b * LL;

  __shared__ float bc[LC * 32];
  {
    const float4* src = (const float4*)(BC + (rowb + t0) * 32);
    float4* dst = (float4*)bc;
#pragma unroll
    for (int i = 0; i < 8; ++i) dst[tid + i * 64] = src[tid + i * 64];
  }

  float a[NN], h[NN];
#pragma unroll
  for (int n = 0; n < NN; ++n) {
    a[n] = expf(-expf(A_log[d * NN + n]));
    h[n] = 0.f;
  }
  __syncthreads();

  const float* xp = XC + (rowb + t0) * DD + d;
  float xc = *xp;
  for (int t = 0; t < LC; ++t) {
    float xc_n = (t + 1 < LC) ? xp[(t + 1) * DD] : 0.f;
#pragma unroll
    for (int n = 0; n < NN; ++n) h[n] = a[n] * h[n] + xc * bc[t * 32 + n];
    xc = xc_n;
  }
  float* sp = S + (((size_t)(b * NC + c)) * DD + d) * NN;
#pragma unroll
  for (int n = 0; n < NN; ++n) sp[n] = h[n];
}

// ---------------------------------------------------------------------------
// Scan phase 2: sequential carry over chunks (S -> H0 in place) + fs mean.
// ---------------------------------------------------------------------------
__global__ __launch_bounds__(256) void scan_carry_k(
    float* __restrict__ S, const float* __restrict__ A_log,
    float* __restrict__ fs) {
  const int idx = blockIdx.x * 256 + threadIdx.x;
  const int n = idx & (NN - 1);
  const int d = (idx / NN) & (DD - 1);
  const int b = idx / (NN * DD);

  const float aLC = expf(-(float)LC * expf(A_log[d * NN + n]));
  float h = 0.f;
  for (int c = 0; c < NC; ++c) {
    size_t off = (((size_t)(b * NC + c)) * DD + d) * NN + n;
    float s = S[off];
    S[off] = h;
    h = aLC * h + s;
  }
  __shared__ float red[256];
  red[threadIdx.x] = h * (1.f / (float)DD);
  __syncthreads();
  if (threadIdx.x < NN) {
    float sum = 0.f;
#pragma unroll
    for (int i = 0; i < 16; ++i) sum += red[i * NN + threadIdx.x];
    atomicAdd(&fs[b * NN + threadIdx.x], sum);
  }
}

// ---------------------------------------------------------------------------
// Scan phase 3: replay from H0, y*silu(gate), write Y1 as bf16 for out-proj.
// ---------------------------------------------------------------------------
__global__ __launch_bounds__(64) void scan_final_k(
    const float* __restrict__ XC, const float* __restrict__ XG,
    const float* __restrict__ BC, const float* __restrict__ A_log,
    const float* __restrict__ D_param, const float* __restrict__ H0,
    ushort_t* __restrict__ Y1b) {
  const int b = blockIdx.x, c = blockIdx.y;
  const int tid = threadIdx.x;
  const int d = blockIdx.z * 64 + tid;
  const int t0 = c * LC;
  const size_t rowb = (size_t)b * LL;

  __shared__ float bc[LC * 32];
  {
    const float4* src = (const float4*)(BC + (rowb + t0) * 32);
    float4* dst = (float4*)bc;
#pragma unroll
    for (int i = 0; i < 8; ++i) dst[tid + i * 64] = src[tid + i * 64];
  }

  float a[NN], h[NN];
  const float* hp = H0 + (((size_t)(b * NC + c)) * DD + d) * NN;
#pragma unroll
  for (int n = 0; n < NN; ++n) {
    a[n] = expf(-expf(A_log[d * NN + n]));
    h[n] = hp[n];
  }
  const float Dp = D_param[d];
  __syncthreads();

  const float* xp = XC + (rowb + t0) * DD + d;
  const float* gp = XG + (rowb + t0) * 2048 + DD + d;
  ushort_t* yp = Y1b + (rowb + t0) * DD + d;
  float xc = *xp, gate = *gp;
  for (int t = 0; t < LC; ++t) {
    float xc_n = 0.f, g_n = 0.f;
    if (t + 1 < LC) {
      xc_n = xp[(t + 1) * DD];
      g_n = gp[(t + 1) * 2048];
    }
    float y = Dp * xc;
#pragma unroll
    for (int n = 0; n < NN; ++n) {
      h[n] = a[n] * h[n] + xc * bc[t * 32 + n];
      y += bc[t * 32 + 16 + n] * h[n];
    }
    float sg = gate / (1.f + __expf(-gate));
    yp[t * DD] = f2bf(y * sg);
    xc = xc_n;
    gate = g_n;
  }
}

// ---------------------------------------------------------------------------
extern "C" void kernel_launch(void* const* d_in, const int* in_sizes, int n_in,
                              void* d_out, int out_size, void* d_ws,
                              size_t ws_size, hipStream_t stream) {
  const float* x = (const float*)d_in[0];
  const float* W_in = (const float*)d_in[1];
  const float* b_in = (const float*)d_in[2];
  const float* conv_w = (const float*)d_in[3];
  const float* conv_b = (const float*)d_in[4];
  const float* W_x = (const float*)d_in[5];
  const float* b_x = (const float*)d_in[6];
  const float* A_log = (const float*)d_in[7];
  const float* D_param = (const float*)d_in[8];
  const float* W_out = (const float*)d_in[9];
  const float* b_out = (const float*)d_in[10];
  float* out = (float*)d_out;

  // ws layout: f32 then bf16 regions
  float* XG = (float*)d_ws;                    // [8192*2048] f32
  float* XC = XG + (size_t)MM * 2048;          // [8192*1024] f32
  float* BC = XC + (size_t)MM * DD;            // [8192*32] f32
  float* S = BC + (size_t)MM * 32;             // [2*64*1024*16] f32
  ushort_t* Xb = (ushort_t*)(S + (size_t)BB * NC * DD * NN);  // [8192*1024] bf16
  ushort_t* WinT = Xb + (size_t)MM * DD;       // [2048*1024] bf16
  ushort_t* WoutT = WinT + (size_t)2048 * DD;  // [1024*1024] bf16
  ushort_t* Y1b = WoutT + (size_t)DD * DD;     // [8192*1024] bf16

  dim3 blk(256);
  // casts / transposes
  cast_bf16_k<<<dim3((MM * DD) / 1024), blk, 0, stream>>>(x, Xb);
  transpose_cast_k<<<dim3(2048 / 32, 1024 / 32), dim3(32, 8), 0, stream>>>(
      W_in, WinT, 1024, 2048);
  transpose_cast_k<<<dim3(1024 / 32, 1024 / 32), dim3(32, 8), 0, stream>>>(
      W_out, WoutT, 1024, 1024);
  // 1. in-proj (bf16 MFMA): XG = x @ W_in + b_in
  gemm_bt_mfma<<<dim3(2048 / 128, MM / 128), blk, 0, stream>>>(
      Xb, WinT, b_in, XG, 2048);
  // 2. conv + silu -> XC (f32)
  conv_silu_k<<<dim3((MM * DD) / 256), blk, 0, stream>>>(XG, conv_w, conv_b, XC);
  // 3. BC proj (fp32): BC = XC @ W_x + b_x
  gemm_bias_k<<<dim3(1, MM / 64), blk, 0, stream>>>(XC, W_x, b_x, BC, 32);
  // 4. scan phase 1
  scan_local_k<<<dim3(BB, NC, DD / 64), dim3(64), 0, stream>>>(XC, BC, A_log, S);
  // 5. zero final_state
  zero_fs_k<<<dim3(1), dim3(64), 0, stream>>>(out + (size_t)MM * DD);
  // 6. carry + final-state mean
  scan_carry_k<<<dim3((BB * DD * NN) / 256), blk, 0, stream>>>(
      S, A_log, out + (size_t)MM * DD);
  // 7. scan phase 3 -> Y1 bf16
  scan_final_k<<<dim3(BB, NC, DD / 64), dim3(64), 0, stream>>>(
      XC, XG, BC, A_log, D_param, S, Y1b);
  // 8. out-proj (bf16 MFMA): out = Y1 @ W_out + b_out
  gemm_bt_mfma<<<dim3(1024 / 128, MM / 128), blk, 0, stream>>>(
      Y1b, WoutT, b_out, out, 1024);
}

// Round 4
// 305.713 us; speedup vs baseline: 10.0282x; 1.2087x over previous
//
#include <hip/hip_runtime.h>
#include <hip/hip_bf16.h>
#include <math.h>

// Problem constants
#define LL 4096
#define DD 1024
#define NN 16
#define KK 4
#define BB 2
#define MM (BB * LL)   // 8192
#define NC 64          // scan chunks
#define LC 64          // chunk length (NC*LC == LL)

typedef unsigned short ushort_t;
typedef short s16x8 __attribute__((ext_vector_type(8)));
typedef float f32x4 __attribute__((ext_vector_type(4)));
typedef unsigned int u32;

__device__ __forceinline__ ushort_t f2bf(float f) {
  __hip_bfloat16 h = __float2bfloat16(f);
  return *reinterpret_cast<ushort_t*>(&h);
}

// ---------------------------------------------------------------------------
// bf16 MFMA GEMM, B-transposed: C[M,N] = A[M,K] @ BT[N,K]^T + bias, K=1024.
// 128x128 tile, BK=32, 256 threads (4 waves, 2x2), 16x16x32 MFMA,
// global_load_lds width-16 staging (m97 structure).
// ---------------------------------------------------------------------------
__global__ __launch_bounds__(256) void gemm_bt_mfma(
    const ushort_t* __restrict__ A,   // [M,K] bf16
    const ushort_t* __restrict__ BT,  // [N,K] bf16
    const float* __restrict__ bias,
    float* __restrict__ C, int N) {
  constexpr int K = 1024;
  __shared__ ushort_t As[128 * 32];
  __shared__ ushort_t Bs[128 * 32];

  const int tid = threadIdx.x;
  const int lane = tid & 63;
  const int w = tid >> 6;            // wave 0..3
  const int wm = w & 1, wn = w >> 1; // 2x2 wave grid over the 128x128 tile
  const int row0 = blockIdx.y * 128;
  const int col0 = blockIdx.x * 128;

  const int lrow = lane >> 2;        // 0..15: row within 16-row group
  const int lk = (lane & 3) * 8;     // 0,8,16,24: k-chunk (8 bf16 = 16B)

  f32x4 acc[4][4];
#pragma unroll
  for (int i = 0; i < 4; ++i)
#pragma unroll
    for (int j = 0; j < 4; ++j) acc[i][j] = (f32x4){0.f, 0.f, 0.f, 0.f};

  const int frow = lane & 15;
  const int quad = lane >> 4;

  for (int k0 = 0; k0 < K; k0 += 32) {
#pragma unroll
    for (int it = 0; it < 2; ++it) {
      int r = it * 64 + w * 16;  // wave-uniform 16-row group
      __builtin_amdgcn_global_load_lds(
          (const __attribute__((address_space(1))) u32*)(A + (size_t)(row0 + r + lrow) * K + k0 + lk),
          (__attribute__((address_space(3))) u32*)(As + r * 32), 16, 0, 0);
      __builtin_amdgcn_global_load_lds(
          (const __attribute__((address_space(1))) u32*)(BT + (size_t)(col0 + r + lrow) * K + k0 + lk),
          (__attribute__((address_space(3))) u32*)(Bs + r * 32), 16, 0, 0);
    }
    __syncthreads();

    s16x8 af[4], bf[4];
#pragma unroll
    for (int mi = 0; mi < 4; ++mi)
      af[mi] = *(const s16x8*)&As[(wm * 64 + mi * 16 + frow) * 32 + quad * 8];
#pragma unroll
    for (int ni = 0; ni < 4; ++ni)
      bf[ni] = *(const s16x8*)&Bs[(wn * 64 + ni * 16 + frow) * 32 + quad * 8];
#pragma unroll
    for (int mi = 0; mi < 4; ++mi)
#pragma unroll
      for (int ni = 0; ni < 4; ++ni)
        acc[mi][ni] = __builtin_amdgcn_mfma_f32_16x16x32_bf16(
            af[mi], bf[ni], acc[mi][ni], 0, 0, 0);
    __syncthreads();
  }

  // Epilogue: C/D layout col=lane&15, row=quad*4+reg
#pragma unroll
  for (int mi = 0; mi < 4; ++mi) {
#pragma unroll
    for (int ni = 0; ni < 4; ++ni) {
      int col = col0 + wn * 64 + ni * 16 + frow;
      float b = bias[col];
#pragma unroll
      for (int r = 0; r < 4; ++r) {
        int row = row0 + wm * 64 + mi * 16 + quad * 4 + r;
        C[(size_t)row * N + col] = acc[mi][ni][r] + b;
      }
    }
  }
}

// ---------------------------------------------------------------------------
// BC projection, bf16 MFMA: BC[M,32] = XCb[M,1024] @ WxT[32,1024]^T + b_x.
// 32x32 tile, 128 threads (2 waves stacked in m), 256 blocks -> full CU use.
// Memory-bound (reads XCb once); MFMA just rides along.
// ---------------------------------------------------------------------------
__global__ __launch_bounds__(128) void bc_mfma_k(
    const ushort_t* __restrict__ A,   // XCb [M,1024]
    const ushort_t* __restrict__ BT,  // WxT [32,1024]
    const float* __restrict__ bias,   // [32]
    float* __restrict__ C) {          // BC [M,32]
  constexpr int K = 1024;
  __shared__ ushort_t As[32 * 32];
  __shared__ ushort_t Bs[32 * 32];

  const int tid = threadIdx.x;
  const int lane = tid & 63;
  const int w = tid >> 6;        // 0..1
  const int row0 = blockIdx.x * 32;
  const int lrow = lane >> 2;
  const int lk = (lane & 3) * 8;
  const int frow = lane & 15;
  const int quad = lane >> 4;

  f32x4 acc[2];
  acc[0] = (f32x4){0.f, 0.f, 0.f, 0.f};
  acc[1] = (f32x4){0.f, 0.f, 0.f, 0.f};

  for (int k0 = 0; k0 < K; k0 += 32) {
    // A: wave w stages rows [w*16, w*16+16)
    __builtin_amdgcn_global_load_lds(
        (const __attribute__((address_space(1))) u32*)(A + (size_t)(row0 + w * 16 + lrow) * K + k0 + lk),
        (__attribute__((address_space(3))) u32*)(As + (w * 16) * 32), 16, 0, 0);
    // B: wave w stages BT rows [w*16, w*16+16)
    __builtin_amdgcn_global_load_lds(
        (const __attribute__((address_space(1))) u32*)(BT + (size_t)(w * 16 + lrow) * K + k0 + lk),
        (__attribute__((address_space(3))) u32*)(Bs + (w * 16) * 32), 16, 0, 0);
    __syncthreads();

    s16x8 af = *(const s16x8*)&As[(w * 16 + frow) * 32 + quad * 8];
    s16x8 bf0 = *(const s16x8*)&Bs[(frow)*32 + quad * 8];
    s16x8 bf1 = *(const s16x8*)&Bs[(16 + frow) * 32 + quad * 8];
    acc[0] = __builtin_amdgcn_mfma_f32_16x16x32_bf16(af, bf0, acc[0], 0, 0, 0);
    acc[1] = __builtin_amdgcn_mfma_f32_16x16x32_bf16(af, bf1, acc[1], 0, 0, 0);
    __syncthreads();
  }

#pragma unroll
  for (int ni = 0; ni < 2; ++ni) {
    int col = ni * 16 + frow;
    float b = bias[col];
#pragma unroll
    for (int r = 0; r < 4; ++r) {
      int row = row0 + w * 16 + quad * 4 + r;
      C[(size_t)row * 32 + col] = acc[ni][r] + b;
    }
  }
}

// ---------------------------------------------------------------------------
// fp32 -> bf16 cast (vectorized, 4 floats/thread)
// ---------------------------------------------------------------------------
__global__ __launch_bounds__(256) void cast_bf16_k(
    const float* __restrict__ src, ushort_t* __restrict__ dst) {
  int i = blockIdx.x * 256 + threadIdx.x;
  float4 v = ((const float4*)src)[i];
  ushort4 o;
  o.x = f2bf(v.x); o.y = f2bf(v.y); o.z = f2bf(v.z); o.w = f2bf(v.w);
  ((ushort4*)dst)[i] = o;
}

// ---------------------------------------------------------------------------
// W [K,N] fp32 -> WT [N,K] bf16 (tiled transpose via LDS)
// ---------------------------------------------------------------------------
__global__ __launch_bounds__(256) void transpose_cast_k(
    const float* __restrict__ W, ushort_t* __restrict__ WT, int K, int N) {
  __shared__ float t[32][33];
  int nb = blockIdx.x * 32, kb = blockIdx.y * 32;
  int tx = threadIdx.x, ty = threadIdx.y;  // (32,8)
#pragma unroll
  for (int i = 0; i < 32; i += 8)
    t[ty + i][tx] = W[(size_t)(kb + ty + i) * N + nb + tx];
  __syncthreads();
#pragma unroll
  for (int i = 0; i < 32; i += 8)
    WT[(size_t)(nb + ty + i) * K + kb + tx] = f2bf(t[tx][ty + i]);
}

// ---------------------------------------------------------------------------
// Depthwise causal conv (left pad K-1) + SiLU.
// XG [M,2048] -> XC [M,1024] f32 AND XCb bf16 (for the BC projection).
// ---------------------------------------------------------------------------
__global__ __launch_bounds__(256) void conv_silu_k(
    const float* __restrict__ XG, const float* __restrict__ conv_w,
    const float* __restrict__ conv_b, float* __restrict__ XC,
    ushort_t* __restrict__ XCb) {
  int idx = blockIdx.x * 256 + threadIdx.x;
  int d = idx & (DD - 1);
  int m = idx >> 10;
  int b = m >> 12;
  int l = m & (LL - 1);
  float v = conv_b[d];
#pragma unroll
  for (int k = 0; k < KK; ++k) {
    int li = l + k - (KK - 1);
    if (li >= 0) v += XG[((size_t)(b * LL + li)) * 2048 + d] * conv_w[d * KK + k];
  }
  float s = v / (1.f + __expf(-v));
  XC[(size_t)m * DD + d] = s;
  XCb[(size_t)m * DD + d] = f2bf(s);
}

__global__ void zero_fs_k(float* fs) {
  if (threadIdx.x < 32) fs[threadIdx.x] = 0.f;
}

// ---------------------------------------------------------------------------
// Scan phase 1: per-chunk local scan from h=0; store chunk end-state S.
// ---------------------------------------------------------------------------
__global__ __launch_bounds__(64) void scan_local_k(
    const float* __restrict__ XC, const float* __restrict__ BC,
    const float* __restrict__ A_log, float* __restrict__ S) {
  const int b = blockIdx.x, c = blockIdx.y;
  const int tid = threadIdx.x;
  const int d = blockIdx.z * 64 + tid;
  const int t0 = c * LC;
  const size_t rowb = (size_t)b * LL;

  __shared__ float bc[LC * 32];
  {
    const float4* src = (const float4*)(BC + (rowb + t0) * 32);
    float4* dst = (float4*)bc;
#pragma unroll
    for (int i = 0; i < 8; ++i) dst[tid + i * 64] = src[tid + i * 64];
  }

  float a[NN], h[NN];
#pragma unroll
  for (int n = 0; n < NN; ++n) {
    a[n] = expf(-expf(A_log[d * NN + n]));
    h[n] = 0.f;
  }
  __syncthreads();

  const float* xp = XC + (rowb + t0) * DD + d;
  float xc = *xp;
  for (int t = 0; t < LC; ++t) {
    float xc_n = (t + 1 < LC) ? xp[(t + 1) * DD] : 0.f;
#pragma unroll
    for (int n = 0; n < NN; ++n) h[n] = a[n] * h[n] + xc * bc[t * 32 + n];
    xc = xc_n;
  }
  float* sp = S + (((size_t)(b * NC + c)) * DD + d) * NN;
#pragma unroll
  for (int n = 0; n < NN; ++n) sp[n] = h[n];
}

// ---------------------------------------------------------------------------
// Scan phase 2: sequential carry over chunks (S -> H0 in place) + fs mean.
// ---------------------------------------------------------------------------
__global__ __launch_bounds__(256) void scan_carry_k(
    float* __restrict__ S, const float* __restrict__ A_log,
    float* __restrict__ fs) {
  const int idx = blockIdx.x * 256 + threadIdx.x;
  const int n = idx & (NN - 1);
  const int d = (idx / NN) & (DD - 1);
  const int b = idx / (NN * DD);

  const float aLC = expf(-(float)LC * expf(A_log[d * NN + n]));
  float h = 0.f;
  for (int c = 0; c < NC; ++c) {
    size_t off = (((size_t)(b * NC + c)) * DD + d) * NN + n;
    float s = S[off];
    S[off] = h;
    h = aLC * h + s;
  }
  __shared__ float red[256];
  red[threadIdx.x] = h * (1.f / (float)DD);
  __syncthreads();
  if (threadIdx.x < NN) {
    float sum = 0.f;
#pragma unroll
    for (int i = 0; i < 16; ++i) sum += red[i * NN + threadIdx.x];
    atomicAdd(&fs[b * NN + threadIdx.x], sum);
  }
}

// ---------------------------------------------------------------------------
// Scan phase 3: replay from H0, y*silu(gate), write Y1 as bf16 for out-proj.
// ---------------------------------------------------------------------------
__global__ __launch_bounds__(64) void scan_final_k(
    const float* __restrict__ XC, const float* __restrict__ XG,
    const float* __restrict__ BC, const float* __restrict__ A_log,
    const float* __restrict__ D_param, const float* __restrict__ H0,
    ushort_t* __restrict__ Y1b) {
  const int b = blockIdx.x, c = blockIdx.y;
  const int tid = threadIdx.x;
  const int d = blockIdx.z * 64 + tid;
  const int t0 = c * LC;
  const size_t rowb = (size_t)b * LL;

  __shared__ float bc[LC * 32];
  {
    const float4* src = (const float4*)(BC + (rowb + t0) * 32);
    float4* dst = (float4*)bc;
#pragma unroll
    for (int i = 0; i < 8; ++i) dst[tid + i * 64] = src[tid + i * 64];
  }

  float a[NN], h[NN];
  const float* hp = H0 + (((size_t)(b * NC + c)) * DD + d) * NN;
#pragma unroll
  for (int n = 0; n < NN; ++n) {
    a[n] = expf(-expf(A_log[d * NN + n]));
    h[n] = hp[n];
  }
  const float Dp = D_param[d];
  __syncthreads();

  const float* xp = XC + (rowb + t0) * DD + d;
  const float* gp = XG + (rowb + t0) * 2048 + DD + d;
  ushort_t* yp = Y1b + (rowb + t0) * DD + d;
  float xc = *xp, gate = *gp;
  for (int t = 0; t < LC; ++t) {
    float xc_n = 0.f, g_n = 0.f;
    if (t + 1 < LC) {
      xc_n = xp[(t + 1) * DD];
      g_n = gp[(t + 1) * 2048];
    }
    float y = Dp * xc;
#pragma unroll
    for (int n = 0; n < NN; ++n) {
      h[n] = a[n] * h[n] + xc * bc[t * 32 + n];
      y += bc[t * 32 + 16 + n] * h[n];
    }
    float sg = gate / (1.f + __expf(-gate));
    yp[t * DD] = f2bf(y * sg);
    xc = xc_n;
    gate = g_n;
  }
}

// ---------------------------------------------------------------------------
extern "C" void kernel_launch(void* const* d_in, const int* in_sizes, int n_in,
                              void* d_out, int out_size, void* d_ws,
                              size_t ws_size, hipStream_t stream) {
  const float* x = (const float*)d_in[0];
  const float* W_in = (const float*)d_in[1];
  const float* b_in = (const float*)d_in[2];
  const float* conv_w = (const float*)d_in[3];
  const float* conv_b = (const float*)d_in[4];
  const float* W_x = (const float*)d_in[5];
  const float* b_x = (const float*)d_in[6];
  const float* A_log = (const float*)d_in[7];
  const float* D_param = (const float*)d_in[8];
  const float* W_out = (const float*)d_in[9];
  const float* b_out = (const float*)d_in[10];
  float* out = (float*)d_out;

  // ws layout: f32 regions then bf16 regions
  float* XG = (float*)d_ws;                    // [8192*2048] f32
  float* XC = XG + (size_t)MM * 2048;          // [8192*1024] f32
  float* BC = XC + (size_t)MM * DD;            // [8192*32] f32
  float* S = BC + (size_t)MM * 32;             // [2*64*1024*16] f32
  ushort_t* Xb = (ushort_t*)(S + (size_t)BB * NC * DD * NN);  // [8192*1024] bf16
  ushort_t* WinT = Xb + (size_t)MM * DD;       // [2048*1024] bf16
  ushort_t* WoutT = WinT + (size_t)2048 * DD;  // [1024*1024] bf16
  ushort_t* Y1b = WoutT + (size_t)DD * DD;     // [8192*1024] bf16
  ushort_t* XCb = Y1b + (size_t)MM * DD;       // [8192*1024] bf16
  ushort_t* WxT = XCb + (size_t)MM * DD;       // [32*1024] bf16

  dim3 blk(256);
  // casts / transposes
  cast_bf16_k<<<dim3((MM * DD) / 1024), blk, 0, stream>>>(x, Xb);
  transpose_cast_k<<<dim3(2048 / 32, 1024 / 32), dim3(32, 8), 0, stream>>>(
      W_in, WinT, 1024, 2048);
  transpose_cast_k<<<dim3(1024 / 32, 1024 / 32), dim3(32, 8), 0, stream>>>(
      W_out, WoutT, 1024, 1024);
  transpose_cast_k<<<dim3(1, 1024 / 32), dim3(32, 8), 0, stream>>>(
      W_x, WxT, 1024, 32);
  // 1. in-proj (bf16 MFMA): XG = x @ W_in + b_in
  gemm_bt_mfma<<<dim3(2048 / 128, MM / 128), blk, 0, stream>>>(
      Xb, WinT, b_in, XG, 2048);
  // 2. conv + silu -> XC (f32) + XCb (bf16)
  conv_silu_k<<<dim3((MM * DD) / 256), blk, 0, stream>>>(XG, conv_w, conv_b,
                                                         XC, XCb);
  // 3. BC proj (bf16 MFMA): BC = x_conv @ W_x + b_x
  bc_mfma_k<<<dim3(MM / 32), dim3(128), 0, stream>>>(XCb, WxT, b_x, BC);
  // 4. scan phase 1
  scan_local_k<<<dim3(BB, NC, DD / 64), dim3(64), 0, stream>>>(XC, BC, A_log, S);
  // 5. zero final_state
  zero_fs_k<<<dim3(1), dim3(64), 0, stream>>>(out + (size_t)MM * DD);
  // 6. carry + final-state mean
  scan_carry_k<<<dim3((BB * DD * NN) / 256), blk, 0, stream>>>(
      S, A_log, out + (size_t)MM * DD);
  // 7. scan phase 3 -> Y1 bf16
  scan_final_k<<<dim3(BB, NC, DD / 64), dim3(64), 0, stream>>>(
      XC, XG, BC, A_log, D_param, S, Y1b);
  // 8. out-proj (bf16 MFMA): out = Y1 @ W_out + b_out
  gemm_bt_mfma<<<dim3(1024 / 128, MM / 128), blk, 0, stream>>>(
      Y1b, WoutT, b_out, out, 1024);
}